// Round 7
// baseline (187.483 us; speedup 1.0000x reference)
//
#include <hip/hip_runtime.h>
#include <math.h>

#define N_ROWS  32768
#define K_CODES 1024
#define D_DIM   64
#define NSPLIT  4            // K-splits (256 codes each)
#define C_SHIFT 30.0f        // logit shift keeps exp2 in fp32 range
#define LOG2E_F 1.4426950408889634f
#define LN2_F   0.6931471805599453f

// ---- ws float-index layout ----
#define WS_HIST   0                       // [1024] histogram (zeroed by prep)
#define WS_ACC_H  1024                    // entropy sum
#define WS_ACC_C  1025                    // commitment sq-diff sum
#define WS_CNT    1027                    // combine completion counter (int bits)
#define WS_E2C    6144                    // [1024] ||e||^2 + C_SHIFT (legacy order)
#define PART_STRIDE (NSPLIT * N_ROWS)     // 131072
#define WS_PART_S  8192
#define WS_PART_U  (8192 + PART_STRIDE)
#define WS_PART_AB (8192 + 2 * PART_STRIDE)   // packed i1*1024+i2 (as float)
#define WS_EB      (8192 + 3 * PART_STRIDE)   // 401408; 64 chunks x 260 f4
#define WS_GP      467968                 // 16 x 4096 gram partials (no zero needed)
#define CHUNK_F4  260                     // float4s per chunk record
#define MAIN_CHUNKS 16                    // 16-code chunks per K-split

// ---- out float-index layout (reference return order, concatenated) ----
#define OUT_Q      0
#define OUT_COMMIT 2097152
#define OUT_ORTHO  2097153
#define OUT_ENT    2097154
#define OUT_PERP   2097155
#define OUT_COV    2097156
#define OUT_IDX    2097157

typedef __attribute__((ext_vector_type(8))) _Float16 f16x8;  // 8 f16 = 4 VGPR
typedef __attribute__((ext_vector_type(4))) float f32x4;

// Bit-identical replica of the legacy fp32 logit chain (for candidate rescue)
__device__ inline float exact_g(const float4* X, const float* __restrict__ emb,
                                int k, float e2ck) {
    const float4* e4 = (const float4*)(emb + (size_t)k * D_DIM);
    float d0 = 0.f, d1 = 0.f, d2 = 0.f, d3 = 0.f;
#pragma unroll
    for (int j = 0; j < 16; j += 4) {
        float4 ea = e4[j], eb = e4[j + 1], ec = e4[j + 2], ed = e4[j + 3];
        float4 xa = X[j], xb = X[j + 1], xc = X[j + 2], xd = X[j + 3];
        d0 = fmaf(ea.x, xa.x, d0); d0 = fmaf(ea.y, xa.y, d0);
        d0 = fmaf(ea.z, xa.z, d0); d0 = fmaf(ea.w, xa.w, d0);
        d1 = fmaf(eb.x, xb.x, d1); d1 = fmaf(eb.y, xb.y, d1);
        d1 = fmaf(eb.z, xb.z, d1); d1 = fmaf(eb.w, xb.w, d1);
        d2 = fmaf(ec.x, xc.x, d2); d2 = fmaf(ec.y, xc.y, d2);
        d2 = fmaf(ec.z, xc.z, d2); d2 = fmaf(ec.w, xc.w, d2);
        d3 = fmaf(ed.x, xd.x, d3); d3 = fmaf(ed.y, xd.y, d3);
        d3 = fmaf(ed.z, xd.z, d3); d3 = fmaf(ed.w, xd.w, d3);
    }
    return fmaf(2.0f, (d0 + d1) + (d2 + d3), -e2ck);
}

// fp16x2 decomposition of 8 floats -> (hi, mid) f16x8 pair.
__device__ inline void decomp2x8(const float* v, f16x8& h, f16x8& m) {
#pragma unroll
    for (int i = 0; i < 8; ++i) {
        _Float16 hh = (_Float16)v[i];
        h[i] = hh;
        m[i] = (_Float16)(v[i] - (float)hh);
    }
}

// Blocks 0..15: E-fragment fp16x2 decomposition + ||e||^2 (+ zero hist/accs).
// Blocks 16..31: ortho gram partials -> per-block slots (non-atomic, no memset).
__global__ __launch_bounds__(256) void vq_prep_ortho(const float* __restrict__ emb,
                                                     const float* __restrict__ cc,
                                                     float* __restrict__ ws) {
    __shared__ float srows[64][64];
    __shared__ float rn2[64];
    const int t = threadIdx.x;

    if (blockIdx.x < 16) {
        // zeroing duty: blocks 0..3 clear the histogram; block 0 clears scalars.
        if (blockIdx.x < 4) ws[WS_HIST + blockIdx.x * 256 + t] = 0.f;
        if (blockIdx.x == 0 && t < 4) ws[WS_ACC_H + t] = 0.f;   // accs + cnt

        const int tid  = blockIdx.x * 256 + t;            // 0..4095
        const int c    = tid >> 6;
        const int lane = tid & 63;
        const int col  = lane & 15;
        const int kg   = lane >> 4;
        const int code = c * 16 + col;
        float4* EB4 = (float4*)(ws + WS_EB);
#pragma unroll
        for (int s = 0; s < 2; ++s) {
            const float* ep = emb + (size_t)code * D_DIM + s * 32 + kg * 8;
            float4 A4 = *(const float4*)ep;
            float4 B4 = *(const float4*)(ep + 4);
            float v[8] = {A4.x, A4.y, A4.z, A4.w, B4.x, B4.y, B4.z, B4.w};
            union { f16x8 h; float4 f; } th, tm;
            decomp2x8(v, th.h, tm.h);
            const int base = c * CHUNK_F4;
            EB4[base + (s * 2 + 0) * 64 + lane] = th.f;   // hi  frag, k-step s
            EB4[base + (s * 2 + 1) * 64 + lane] = tm.f;   // mid frag, k-step s
        }
        if (kg == 0) {
            // legacy sequential order -> ws[WS_E2C] bitwise matches prior rounds
            const float4* e4 = (const float4*)(emb + (size_t)code * D_DIM);
            float ssum = 0.f;
#pragma unroll
            for (int j = 0; j < 16; ++j) {
                float4 v = e4[j];
                ssum += v.x * v.x + v.y * v.y + v.z * v.z + v.w * v.w;
            }
            float e2c = ssum + C_SHIFT;
            ws[WS_E2C + code] = e2c;
            ((float*)(EB4 + c * CHUNK_F4 + 256))[col] = e2c * LOG2E_F;  // base-2
        }
        return;
    }

    // ---- ortho: block b owns codes [64b, 64b+64); partial 64x64 gram
    const int ob = blockIdx.x - 16;
    const int k0 = ob * 64;
    const int rb = t >> 4;            // 0..15
    const int c4 = (t & 15) << 2;     // float4 col

#pragma unroll
    for (int i = 0; i < 4; ++i) {
        const int r = i * 16 + rb;
        float4 v = *(const float4*)(emb + (size_t)(k0 + r) * D_DIM + c4);
        *(float4*)(&srows[r][c4]) = v;
        float ss = v.x * v.x + v.y * v.y + v.z * v.z + v.w * v.w;
        ss += __shfl_down(ss, 8, 16);
        ss += __shfl_down(ss, 4, 16);
        ss += __shfl_down(ss, 2, 16);
        ss += __shfl_down(ss, 1, 16);
        if ((t & 15) == 0) {
            float nrm = fmaxf(sqrtf(ss), 1e-12f);
            float m = (cc[k0 + r] >= 1.0f) ? 1.0f : 0.0f;
            rn2[r] = m / (nrm * nrm);     // rnorm^2, folded into A side
        }
    }
    __syncthreads();

    const int a  = t >> 2;
    const int b0 = (t & 3) << 4;
    float acc[16];
#pragma unroll
    for (int i = 0; i < 16; ++i) acc[i] = 0.f;

#pragma unroll 4
    for (int k = 0; k < 64; ++k) {
        float na = srows[k][a] * rn2[k];
        const float* rbp = &srows[k][b0];
#pragma unroll
        for (int i = 0; i < 16; ++i) acc[i] = fmaf(na, rbp[i], acc[i]);
    }
#pragma unroll
    for (int i = 0; i < 16; ++i)
        ws[WS_GP + ob * 4096 + a * 64 + b0 + i] = acc[i];   // own slot, no atomic
}

#define MFMA_F16 __builtin_amdgcn_mfma_f32_16x16x32_f16

// 2048 blocks x 256 thr. Block = (row-group of 64, K-split of 256 codes).
// Wave = 16 rows x 256 codes; fp16x2 4-term MFMA emulation.
// DESIGN-FOR-64: total live state ~60 regs (xa 16 + B 17 + acc 4 + epi 20 +
// addr) so the allocator's PREFERRED 64-reg/8-wave tier holds everything --
// no AGPR shuttle (r0/r1/r3/r5 failure mode), no scratch (r4), no attribute.
// 8 waves/SIMD TLP hides the L1-bound B-frag stream (~570 MB, ~15 us floor).
__global__ __launch_bounds__(256)
void vq_main(const float* __restrict__ inp, float* __restrict__ ws) {
    const int t    = threadIdx.x;
    const int lane = t & 63;
    const int wave = t >> 6;
    const int col  = lane & 15;
    const int kg   = lane >> 4;
    const int rg   = blockIdx.x >> 2;      // row group 0..511 (64 rows)
    const int sp   = blockIdx.x & 3;       // k split 0..3 (256 codes)
    const int row  = rg * 64 + wave * 16 + col;

    // A-frags: hi/mid per k-step
    f16x8 xh0, xm0, xh1, xm1;
    {
        const float* xp = inp + (size_t)row * D_DIM + kg * 8;
        float4 A4 = *(const float4*)xp;
        float4 B4 = *(const float4*)(xp + 4);
        float v[8] = {A4.x, A4.y, A4.z, A4.w, B4.x, B4.y, B4.z, B4.w};
        decomp2x8(v, xh0, xm0);
        A4 = *(const float4*)(xp + 32);
        B4 = *(const float4*)(xp + 36);
        float w[8] = {A4.x, A4.y, A4.z, A4.w, B4.x, B4.y, B4.z, B4.w};
        decomp2x8(w, xh1, xm1);
    }

    const float4* EBp = (const float4*)(ws + WS_EB)
                      + (size_t)sp * MAIN_CHUNKS * CHUNK_F4;

    float sa[4], ua[4], m1[4], m2[4];
    int i12[4];
#pragma unroll
    for (int q = 0; q < 4; ++q) {
        sa[q] = 0.f; ua[q] = 0.f;
        m1[q] = -1e30f; m2[q] = -1e30f;
        i12[q] = 0;
    }

#pragma unroll 1
    for (int c = 0; c < MAIN_CHUNKS; ++c) {
        const float4* p = EBp + (size_t)c * CHUNK_F4;
        const f16x8* pb = (const f16x8*)p;
        f16x8 bh0 = pb[0 * 64 + lane];     // hi,  k-step 0
        f16x8 bm0 = pb[1 * 64 + lane];     // mid, k-step 0
        f16x8 bh1 = pb[2 * 64 + lane];     // hi,  k-step 1
        f16x8 bm1 = pb[3 * 64 + lane];     // mid, k-step 1
        const float e2v = ((const float*)(p + 256))[col];

        f32x4 acc = {0.f, 0.f, 0.f, 0.f};
        acc = MFMA_F16(xh0, bh0, acc, 0, 0, 0);
        acc = MFMA_F16(xh1, bh1, acc, 0, 0, 0);
        acc = MFMA_F16(xm0, bh0, acc, 0, 0, 0);
        acc = MFMA_F16(xm1, bh1, acc, 0, 0, 0);
        acc = MFMA_F16(xh0, bm0, acc, 0, 0, 0);
        acc = MFMA_F16(xh1, bm1, acc, 0, 0, 0);
        acc = MFMA_F16(xm0, bm0, acc, 0, 0, 0);
        acc = MFMA_F16(xm1, bm1, acc, 0, 0, 0);

        const int cb = sp * 256 + c * 16 + col;        // global code index
#pragma unroll
        for (int q = 0; q < 4; ++q) {
            // base-2 shifted logit: g = 2*log2e*dot - log2e*(e2+C_SHIFT)
            float g = fmaf(2.0f * LOG2E_F, acc[q], -e2v);
            float pw;
            asm("v_exp_f32 %0, %1" : "=v"(pw) : "v"(g));   // 2^g
            sa[q] += pw;
            ua[q] = fmaf(pw, g, ua[q]);
            bool gt1 = g > m1[q];
            bool gt2 = g > m2[q];
            int t1 = (cb << 10) | (i12[q] >> 10);          // new i1=cb, i2=old i1
            int t2 = (i12[q] & ~1023) | cb;                // new i2=cb
            i12[q] = gt1 ? t1 : (gt2 ? t2 : i12[q]);
            m2[q] = __builtin_amdgcn_fmed3f(g, m2[q], m1[q]);
            m1[q] = fmaxf(m1[q], g);
        }
    }

    // per-row reduce across the 16 lanes sharing each C-row
#pragma unroll
    for (int off = 1; off < 16; off <<= 1) {
#pragma unroll
        for (int q = 0; q < 4; ++q) {
            sa[q] += __shfl_xor(sa[q], off);
            ua[q] += __shfl_xor(ua[q], off);
            float bm1v = __shfl_xor(m1[q], off);
            float bm2v = __shfl_xor(m2[q], off);
            int   biv  = __shfl_xor(i12[q], off);
            if (bm1v > m1[q]) {
                if (bm2v > m1[q]) {            // both from partner
                    m2[q] = bm2v; i12[q] = biv;
                } else {                        // partner's 1st, our 1st
                    m2[q] = m1[q];
                    i12[q] = (biv & ~1023 & 0xFFFFFC00) | (i12[q] >> 10);
                    i12[q] = ((biv >> 10) << 10) | (i12[q] & 1023);
                }
                m1[q] = bm1v;
            } else if (bm1v > m2[q]) {          // partner's 1st is our 2nd
                m2[q] = bm1v;
                i12[q] = (i12[q] & ~1023) | (biv >> 10);
            }
        }
    }

    if (col == 0) {
#pragma unroll
        for (int q = 0; q < 4; ++q) {
            const int r  = rg * 64 + wave * 16 + kg * 4 + q;
            const int pi = sp * N_ROWS + r;
            ws[WS_PART_S + pi]  = sa[q];
            ws[WS_PART_U + pi]  = ua[q];
            ws[WS_PART_AB + pi] = (float)i12[q];
        }
    }
}

// 512 blocks x 64 thr; thread = row. Merge 4 splits, exact fp32 rescue of <=8
// candidates, epilogue. LAST block (completion counter) runs the finalize.
__global__ __launch_bounds__(64) void vq_combine(const float* __restrict__ inp,
                                                 const float* __restrict__ emb,
                                                 const float* __restrict__ cc,
                                                 float* __restrict__ ws,
                                                 float* __restrict__ out) {
    const int lane = threadIdx.x;
    const int row  = blockIdx.x * 64 + lane;

    float S = 0.f, U2 = 0.f;
    int cand[8];
#pragma unroll
    for (int sp = 0; sp < NSPLIT; ++sp) {
        const int pi = sp * N_ROWS + row;
        S  += ws[WS_PART_S + pi];
        U2 += ws[WS_PART_U + pi];
        int ab = (int)ws[WS_PART_AB + pi];
        cand[2 * sp]     = ab >> 10;
        cand[2 * sp + 1] = ab & 1023;
    }
    float U = U2 * LN2_F;                             // base-2 -> nats

    float4 X[16];
    const float4* xr = (const float4*)(inp + (size_t)row * D_DIM);
#pragma unroll
    for (int j = 0; j < 16; ++j) X[j] = xr[j];

    float bestg = -1e30f; int I = K_CODES;
#pragma unroll 2
    for (int j = 0; j < 8; ++j) {
        const int c = cand[j];
        float g = exact_g(X, emb, c, ws[WS_E2C + c]);
        if (g > bestg || (g == bestg && c < I)) { bestg = g; I = c; }
    }

    float H = logf(S) - U / S;                        // per-row entropy (nats)

    out[OUT_IDX + row] = (float)I;
    atomicAdd(&ws[WS_HIST + I], 1.0f);

    const float4* q4 = (const float4*)(emb + (size_t)I * D_DIM);
    float4* oq = (float4*)out + (size_t)row * 16;
    float cs = 0.f;
#pragma unroll
    for (int j = 0; j < 16; ++j) {
        float4 q = q4[j], x = X[j];
        float dx = q.x - x.x, dy = q.y - x.y, dz = q.z - x.z, dw = q.w - x.w;
        cs += dx * dx + dy * dy + dz * dz + dw * dw;
        float4 o;
        o.x = x.x + dx; o.y = x.y + dy; o.z = x.z + dz; o.w = x.w + dw;
        oq[j] = o;
    }
#pragma unroll
    for (int off = 32; off; off >>= 1) {
        H  += __shfl_down(H, off);
        cs += __shfl_down(cs, off);
    }
    if (lane == 0) {
        atomicAdd(&ws[WS_ACC_H], H);
        atomicAdd(&ws[WS_ACC_C], cs);
    }

    // ---- last-block finalize (saves a dispatch) ----
    __threadfence();
    int old = 0;
    if (lane == 0) old = atomicAdd((int*)ws + WS_CNT, 1);
    old = __shfl(old, 0);
    if (old != 511) return;

    float hp = 0.f, gg = 0.f, nu = 0.f;
    for (int k = lane; k < K_CODES; k += 64) {
        float h = __hip_atomic_load(ws + WS_HIST + k, __ATOMIC_RELAXED,
                                    __HIP_MEMORY_SCOPE_AGENT);
        float p = h * (1.0f / (float)N_ROWS);
        hp += p * logf(p + 1e-10f);
        nu += (cc[k] >= 1.0f) ? 1.0f : 0.0f;
    }
    for (int i4 = lane; i4 < 1024; i4 += 64) {        // 4096 gram elems as f4
        float4 s = {0.f, 0.f, 0.f, 0.f};
#pragma unroll 4
        for (int b = 0; b < 16; ++b) {                // gram written last dispatch
            float4 v = *(const float4*)(ws + WS_GP + b * 4096 + i4 * 4);
            s.x += v.x; s.y += v.y; s.z += v.z; s.w += v.w;
        }
        gg += s.x * s.x + s.y * s.y + s.z * s.z + s.w * s.w;
    }
#pragma unroll
    for (int off = 32; off; off >>= 1) {
        hp += __shfl_down(hp, off);
        gg += __shfl_down(gg, off);
        nu += __shfl_down(nu, off);
    }
    if (lane == 0) {
        float H2 = __hip_atomic_load(ws + WS_ACC_H, __ATOMIC_RELAXED,
                                     __HIP_MEMORY_SCOPE_AGENT);
        float C2 = __hip_atomic_load(ws + WS_ACC_C, __ATOMIC_RELAXED,
                                     __HIP_MEMORY_SCOPE_AGENT);
        out[OUT_PERP]   = expf(-hp);
        out[OUT_ENT]    = H2 * (1.0f / (float)N_ROWS) * 0.1f;  // /log2(1024)
        out[OUT_COMMIT] = C2 * (1.0f / ((float)N_ROWS * (float)D_DIM));
        out[OUT_ORTHO]  = gg / (nu * nu) - 1.0f / nu;
        out[OUT_COV]    = nu * (1.0f / (float)K_CODES);
    }
}

extern "C" void kernel_launch(void* const* d_in, const int* in_sizes, int n_in,
                              void* d_out, int out_size, void* d_ws, size_t ws_size,
                              hipStream_t stream) {
    const float* inp = (const float*)d_in[0];   // [16,2048,64]
    const float* emb = (const float*)d_in[1];   // [1024,64]
    const float* cc  = (const float*)d_in[2];   // [1024]
    float* out = (float*)d_out;
    float* ws  = (float*)d_ws;

    vq_prep_ortho<<<32, 256, 0, stream>>>(emb, cc, ws);
    vq_main<<<(N_ROWS / 64) * NSPLIT, 256, 0, stream>>>(inp, ws);
    vq_combine<<<N_ROWS / 64, 64, 0, stream>>>(inp, emb, cc, ws, out);
}

// Round 8
// 184.779 us; speedup vs baseline: 1.0146x; 1.0146x over previous
//
#include <hip/hip_runtime.h>
#include <math.h>

#define N_ROWS  32768
#define K_CODES 1024
#define D_DIM   64
#define NSPLIT  4            // K-splits (256 codes each)
#define C_SHIFT 30.0f        // logit shift keeps exp2 in fp32 range
#define LOG2E_F 1.4426950408889634f
#define LN2_F   0.6931471805599453f
#define TAU     0.25f        // rescue threshold (base-2 logit units); approx
                             // error <= ~1e-3 worst case -> 250x margin

// ---- ws float-index layout ----
#define WS_HIST   0                       // [1024] histogram (zeroed by prep)
#define WS_ACC_H  1024                    // entropy sum (nats)
#define WS_ACC_C  1025                    // commitment sq-diff sum
#define WS_E2C    6144                    // [1024] ||e||^2 + C_SHIFT (legacy order)
#define PART_STRIDE (NSPLIT * N_ROWS)     // 131072
#define WS_PART_S  8192
#define WS_PART_U  (8192 + PART_STRIDE)
#define WS_PART_AB (8192 + 2 * PART_STRIDE)   // packed i1*1024+i2 (as float)
#define WS_PART_M1 (8192 + 3 * PART_STRIDE)   // approx best value per split
#define WS_PART_M2 (8192 + 4 * PART_STRIDE)   // approx 2nd  value per split
#define CHUNK_F4  260                     // float4s per chunk record
#define MAIN_CHUNKS 16                    // 16-code chunks per K-split
#define WS_EB      (8192 + 5 * PART_STRIDE)   // 663552; 64 chunks x 260 f4
#define WS_GP      (WS_EB + 64 * CHUNK_F4 * 4) // 730112; 16 x 4096 gram partials

// ---- out float-index layout (reference return order, concatenated) ----
#define OUT_Q      0
#define OUT_COMMIT 2097152
#define OUT_ORTHO  2097153
#define OUT_ENT    2097154
#define OUT_PERP   2097155
#define OUT_COV    2097156
#define OUT_IDX    2097157

typedef __attribute__((ext_vector_type(8))) _Float16 f16x8;  // 8 f16 = 4 VGPR
typedef __attribute__((ext_vector_type(4))) float f32x4;

// fp16x2 decomposition of 8 floats -> (hi, mid) f16x8 pair.
__device__ inline void decomp2x8(const float* v, f16x8& h, f16x8& m) {
#pragma unroll
    for (int i = 0; i < 8; ++i) {
        _Float16 hh = (_Float16)v[i];
        h[i] = hh;
        m[i] = (_Float16)(v[i] - (float)hh);
    }
}

// Blocks 0..15: E-fragment fp16x2 decomposition + ||e||^2 (+ zero hist/accs).
// Blocks 16..31: ortho gram partials -> per-block slots (non-atomic).
__global__ __launch_bounds__(256) void vq_prep_ortho(const float* __restrict__ emb,
                                                     const float* __restrict__ cc,
                                                     float* __restrict__ ws) {
    __shared__ float srows[64][64];
    __shared__ float rn2[64];
    const int t = threadIdx.x;

    if (blockIdx.x < 16) {
        // zeroing duty: blocks 0..3 clear the histogram; block 0 clears accs.
        if (blockIdx.x < 4) ws[WS_HIST + blockIdx.x * 256 + t] = 0.f;
        if (blockIdx.x == 0 && t < 2) ws[WS_ACC_H + t] = 0.f;

        const int tid  = blockIdx.x * 256 + t;            // 0..4095
        const int c    = tid >> 6;
        const int lane = tid & 63;
        const int col  = lane & 15;
        const int kg   = lane >> 4;
        const int code = c * 16 + col;
        float4* EB4 = (float4*)(ws + WS_EB);
#pragma unroll
        for (int s = 0; s < 2; ++s) {
            const float* ep = emb + (size_t)code * D_DIM + s * 32 + kg * 8;
            float4 A4 = *(const float4*)ep;
            float4 B4 = *(const float4*)(ep + 4);
            float v[8] = {A4.x, A4.y, A4.z, A4.w, B4.x, B4.y, B4.z, B4.w};
            union { f16x8 h; float4 f; } th, tm;
            decomp2x8(v, th.h, tm.h);
            const int base = c * CHUNK_F4;
            EB4[base + (s * 2 + 0) * 64 + lane] = th.f;   // hi  frag, k-step s
            EB4[base + (s * 2 + 1) * 64 + lane] = tm.f;   // mid frag, k-step s
        }
        if (kg == 0) {
            // legacy sequential order -> ws[WS_E2C] bitwise matches prior rounds
            const float4* e4 = (const float4*)(emb + (size_t)code * D_DIM);
            float ssum = 0.f;
#pragma unroll
            for (int j = 0; j < 16; ++j) {
                float4 v = e4[j];
                ssum += v.x * v.x + v.y * v.y + v.z * v.z + v.w * v.w;
            }
            float e2c = ssum + C_SHIFT;
            ws[WS_E2C + code] = e2c;
            ((float*)(EB4 + c * CHUNK_F4 + 256))[col] = e2c * LOG2E_F;  // base-2
        }
        return;
    }

    // ---- ortho: block b owns codes [64b, 64b+64); partial 64x64 gram
    const int ob = blockIdx.x - 16;
    const int k0 = ob * 64;
    const int rb = t >> 4;            // 0..15
    const int c4 = (t & 15) << 2;     // float4 col

#pragma unroll
    for (int i = 0; i < 4; ++i) {
        const int r = i * 16 + rb;
        float4 v = *(const float4*)(emb + (size_t)(k0 + r) * D_DIM + c4);
        *(float4*)(&srows[r][c4]) = v;
        float ss = v.x * v.x + v.y * v.y + v.z * v.z + v.w * v.w;
        ss += __shfl_down(ss, 8, 16);
        ss += __shfl_down(ss, 4, 16);
        ss += __shfl_down(ss, 2, 16);
        ss += __shfl_down(ss, 1, 16);
        if ((t & 15) == 0) {
            float nrm = fmaxf(sqrtf(ss), 1e-12f);
            float m = (cc[k0 + r] >= 1.0f) ? 1.0f : 0.0f;
            rn2[r] = m / (nrm * nrm);     // rnorm^2, folded into A side
        }
    }
    __syncthreads();

    const int a  = t >> 2;
    const int b0 = (t & 3) << 4;
    float acc[16];
#pragma unroll
    for (int i = 0; i < 16; ++i) acc[i] = 0.f;

#pragma unroll 4
    for (int k = 0; k < 64; ++k) {
        float na = srows[k][a] * rn2[k];
        const float* rbp = &srows[k][b0];
#pragma unroll
        for (int i = 0; i < 16; ++i) acc[i] = fmaf(na, rbp[i], acc[i]);
    }
#pragma unroll
    for (int i = 0; i < 16; ++i)
        ws[WS_GP + ob * 4096 + a * 64 + b0 + i] = acc[i];   // own slot, no atomic
}

#define MFMA_F16 __builtin_amdgcn_mfma_f32_16x16x32_f16

// 2048 blocks x 256 thr. Block = (row-group of 64, K-split of 256 codes).
// Wave = 16 rows x 256 codes; fp16x2 4-term MFMA emulation. DESIGN-FOR-64
// (see r7 notes). Unchanged this round except storing m1/m2 values.
__global__ __launch_bounds__(256)
void vq_main(const float* __restrict__ inp, float* __restrict__ ws) {
    const int t    = threadIdx.x;
    const int lane = t & 63;
    const int wave = t >> 6;
    const int col  = lane & 15;
    const int kg   = lane >> 4;
    const int rg   = blockIdx.x >> 2;      // row group 0..511 (64 rows)
    const int sp   = blockIdx.x & 3;       // k split 0..3 (256 codes)
    const int row  = rg * 64 + wave * 16 + col;

    // A-frags: hi/mid per k-step
    f16x8 xh0, xm0, xh1, xm1;
    {
        const float* xp = inp + (size_t)row * D_DIM + kg * 8;
        float4 A4 = *(const float4*)xp;
        float4 B4 = *(const float4*)(xp + 4);
        float v[8] = {A4.x, A4.y, A4.z, A4.w, B4.x, B4.y, B4.z, B4.w};
        decomp2x8(v, xh0, xm0);
        A4 = *(const float4*)(xp + 32);
        B4 = *(const float4*)(xp + 36);
        float w[8] = {A4.x, A4.y, A4.z, A4.w, B4.x, B4.y, B4.z, B4.w};
        decomp2x8(w, xh1, xm1);
    }

    const float4* EBp = (const float4*)(ws + WS_EB)
                      + (size_t)sp * MAIN_CHUNKS * CHUNK_F4;

    float sa[4], ua[4], m1[4], m2[4];
    int i12[4];
#pragma unroll
    for (int q = 0; q < 4; ++q) {
        sa[q] = 0.f; ua[q] = 0.f;
        m1[q] = -1e30f; m2[q] = -1e30f;
        i12[q] = 0;
    }

#pragma unroll 1
    for (int c = 0; c < MAIN_CHUNKS; ++c) {
        const float4* p = EBp + (size_t)c * CHUNK_F4;
        const f16x8* pb = (const f16x8*)p;
        f16x8 bh0 = pb[0 * 64 + lane];     // hi,  k-step 0
        f16x8 bm0 = pb[1 * 64 + lane];     // mid, k-step 0
        f16x8 bh1 = pb[2 * 64 + lane];     // hi,  k-step 1
        f16x8 bm1 = pb[3 * 64 + lane];     // mid, k-step 1
        const float e2v = ((const float*)(p + 256))[col];

        f32x4 acc = {0.f, 0.f, 0.f, 0.f};
        acc = MFMA_F16(xh0, bh0, acc, 0, 0, 0);
        acc = MFMA_F16(xh1, bh1, acc, 0, 0, 0);
        acc = MFMA_F16(xm0, bh0, acc, 0, 0, 0);
        acc = MFMA_F16(xm1, bh1, acc, 0, 0, 0);
        acc = MFMA_F16(xh0, bm0, acc, 0, 0, 0);
        acc = MFMA_F16(xh1, bm1, acc, 0, 0, 0);
        acc = MFMA_F16(xm0, bm0, acc, 0, 0, 0);
        acc = MFMA_F16(xm1, bm1, acc, 0, 0, 0);

        const int cb = sp * 256 + c * 16 + col;        // global code index
#pragma unroll
        for (int q = 0; q < 4; ++q) {
            // base-2 shifted logit: g = 2*log2e*dot - log2e*(e2+C_SHIFT)
            float g = fmaf(2.0f * LOG2E_F, acc[q], -e2v);
            float pw;
            asm("v_exp_f32 %0, %1" : "=v"(pw) : "v"(g));   // 2^g
            sa[q] += pw;
            ua[q] = fmaf(pw, g, ua[q]);
            bool gt1 = g > m1[q];
            bool gt2 = g > m2[q];
            int t1 = (cb << 10) | (i12[q] >> 10);          // new i1=cb, i2=old i1
            int t2 = (i12[q] & ~1023) | cb;                // new i2=cb
            i12[q] = gt1 ? t1 : (gt2 ? t2 : i12[q]);
            m2[q] = __builtin_amdgcn_fmed3f(g, m2[q], m1[q]);
            m1[q] = fmaxf(m1[q], g);
        }
    }

    // per-row reduce across the 16 lanes sharing each C-row
#pragma unroll
    for (int off = 1; off < 16; off <<= 1) {
#pragma unroll
        for (int q = 0; q < 4; ++q) {
            sa[q] += __shfl_xor(sa[q], off);
            ua[q] += __shfl_xor(ua[q], off);
            float bm1v = __shfl_xor(m1[q], off);
            float bm2v = __shfl_xor(m2[q], off);
            int   biv  = __shfl_xor(i12[q], off);
            if (bm1v > m1[q]) {
                if (bm2v > m1[q]) {            // both from partner
                    m2[q] = bm2v; i12[q] = biv;
                } else {                        // partner's 1st, our 1st
                    m2[q] = m1[q];
                    i12[q] = (biv & ~1023 & 0xFFFFFC00) | (i12[q] >> 10);
                    i12[q] = ((biv >> 10) << 10) | (i12[q] & 1023);
                }
                m1[q] = bm1v;
            } else if (bm1v > m2[q]) {          // partner's 1st is our 2nd
                m2[q] = bm1v;
                i12[q] = (i12[q] & ~1023) | (biv >> 10);
            }
        }
    }

    if (col == 0) {
#pragma unroll
        for (int q = 0; q < 4; ++q) {
            const int r  = rg * 64 + wave * 16 + kg * 4 + q;
            const int pi = sp * N_ROWS + r;
            ws[WS_PART_S  + pi] = sa[q];
            ws[WS_PART_U  + pi] = ua[q];
            ws[WS_PART_AB + pi] = (float)i12[q];
            ws[WS_PART_M1 + pi] = m1[q];
            ws[WS_PART_M2 + pi] = m2[q];
        }
    }
}

// 512 blocks x 256 thr; QUAD (4 lanes) per row -> 2048 waves (4x r7's TLP).
// Threshold rescue: only candidates within TAU of the global approx max get
// the exact fp32 eval (expected ~1/row, was 8). exact_g's 4 legacy FMA
// chains map 1:1 onto the quad's lanes -> bit-identical g via 4 shuffles.
__global__ __launch_bounds__(256) void vq_combine(const float* __restrict__ inp,
                                                  const float* __restrict__ emb,
                                                  float* __restrict__ ws,
                                                  float* __restrict__ out) {
    const int t    = threadIdx.x;
    const int lane = t & 63;
    const int l    = t & 3;               // quad lane = chain id
    const int row  = blockIdx.x * 64 + (t >> 2);
    const int qb   = lane & ~3;           // quad base within wave

    // this lane's split-l partials
    const int pi = l * N_ROWS + row;
    float Sl  = ws[WS_PART_S  + pi];
    float Ul  = ws[WS_PART_U  + pi];
    int   ab  = (int)ws[WS_PART_AB + pi];
    float M1l = ws[WS_PART_M1 + pi];
    float M2l = ws[WS_PART_M2 + pi];

    // quad gather: S,U in ascending split order (legacy); Gmax over splits
    float S = 0.f, U2 = 0.f, Gmax = -1e30f;
#pragma unroll
    for (int k = 0; k < 4; ++k) {
        S  += __shfl(Sl, qb + k);
        U2 += __shfl(Ul, qb + k);
        Gmax = fmaxf(Gmax, __shfl(M1l, qb + k));
    }

    // X strided quarter: Xq[k] = X[l + 4k] (serves chains + write + commit)
    float4 Xq[4];
    const float4* xr = (const float4*)(inp + (size_t)row * D_DIM);
#pragma unroll
    for (int k = 0; k < 4; ++k) Xq[k] = xr[l + 4 * k];

    // candidates in legacy order j=0..7 (split asc, i1 before i2)
    float bestg = -1e30f; int I = K_CODES;
#pragma unroll 1
    for (int j = 0; j < 8; ++j) {
        const int sp  = j >> 1;
        const float v = __shfl((j & 1) ? M2l : M1l, qb + sp);
        if (v < Gmax - TAU) continue;      // provably cannot be exact argmax
        const int abo = __shfl(ab, qb + sp);
        const int c   = (j & 1) ? (abo & 1023) : (abo >> 10);
        // lane l: legacy chain d_l = fma chain over e4[l+4k] x X[l+4k]
        const float4* e4 = (const float4*)(emb + (size_t)c * D_DIM);
        float d = 0.f;
#pragma unroll
        for (int k = 0; k < 4; ++k) {
            float4 ev = e4[l + 4 * k];
            float4 xv = Xq[k];
            d = fmaf(ev.x, xv.x, d); d = fmaf(ev.y, xv.y, d);
            d = fmaf(ev.z, xv.z, d); d = fmaf(ev.w, xv.w, d);
        }
        float dA = __shfl(d, qb + 0) + __shfl(d, qb + 1);   // (d0+d1)
        float dB = __shfl(d, qb + 2) + __shfl(d, qb + 3);   // (d2+d3)
        float g  = fmaf(2.0f, dA + dB, -ws[WS_E2C + c]);    // legacy-exact
        if (g > bestg || (g == bestg && c < I)) { bestg = g; I = c; }
    }

    float H = logf(S) - (U2 * LN2_F) / S;  // per-row entropy (nats)

    if (l == 0) {
        out[OUT_IDX + row] = (float)I;
        atomicAdd(&ws[WS_HIST + I], 1.0f);
    }

    // quantized + commitment on the strided quarter (elementwise-identical Q)
    const float4* q4 = (const float4*)(emb + (size_t)I * D_DIM);
    float4* oq = (float4*)out + (size_t)row * 16;
    float cs = 0.f;
#pragma unroll
    for (int k = 0; k < 4; ++k) {
        float4 q = q4[l + 4 * k], x = Xq[k];
        float dx = q.x - x.x, dy = q.y - x.y, dz = q.z - x.z, dw = q.w - x.w;
        cs += dx * dx + dy * dy + dz * dz + dw * dw;
        float4 o;
        o.x = x.x + dx; o.y = x.y + dy; o.z = x.z + dz; o.w = x.w + dw;
        oq[l + 4 * k] = o;
    }

    float Hc = (l == 0) ? H : 0.f;
#pragma unroll
    for (int off = 32; off; off >>= 1) {
        Hc += __shfl_down(Hc, off);
        cs += __shfl_down(cs, off);
    }
    if (lane == 0) {
        atomicAdd(&ws[WS_ACC_H], Hc);
        atomicAdd(&ws[WS_ACC_C], cs);
    }
}

// 1 block x 256 thr. Plain loads: all inputs written by prior dispatches.
__global__ __launch_bounds__(256) void vq_finalize(const float* __restrict__ ws,
                                                   const float* __restrict__ cc,
                                                   float* __restrict__ out) {
    __shared__ float redP[4], redG[4], redN[4];
    const int t = threadIdx.x;
    float hp = 0.f, gg = 0.f, nu = 0.f;
    for (int k = t; k < K_CODES; k += 256) {
        float p = ws[WS_HIST + k] * (1.0f / (float)N_ROWS);
        hp += p * logf(p + 1e-10f);
        nu += (cc[k] >= 1.0f) ? 1.0f : 0.0f;
    }
    for (int i = t; i < 4096; i += 256) {
        float s = 0.f;
#pragma unroll
        for (int b = 0; b < 16; ++b) s += ws[WS_GP + b * 4096 + i];
        gg = fmaf(s, s, gg);
    }
#pragma unroll
    for (int off = 32; off; off >>= 1) {
        hp += __shfl_down(hp, off);
        gg += __shfl_down(gg, off);
        nu += __shfl_down(nu, off);
    }
    if ((t & 63) == 0) { redP[t >> 6] = hp; redG[t >> 6] = gg; redN[t >> 6] = nu; }
    __syncthreads();
    if (t == 0) {
        float hsum = redP[0] + redP[1] + redP[2] + redP[3];
        float gsum = redG[0] + redG[1] + redG[2] + redG[3];
        float nuv  = redN[0] + redN[1] + redN[2] + redN[3];
        out[OUT_PERP]   = expf(-hsum);
        out[OUT_ENT]    = ws[WS_ACC_H] * (1.0f / (float)N_ROWS) * 0.1f; // /log2(1024)
        out[OUT_COMMIT] = ws[WS_ACC_C] * (1.0f / ((float)N_ROWS * (float)D_DIM));
        out[OUT_ORTHO]  = gsum / (nuv * nuv) - 1.0f / nuv;
        out[OUT_COV]    = nuv * (1.0f / (float)K_CODES);
    }
}

extern "C" void kernel_launch(void* const* d_in, const int* in_sizes, int n_in,
                              void* d_out, int out_size, void* d_ws, size_t ws_size,
                              hipStream_t stream) {
    const float* inp = (const float*)d_in[0];   // [16,2048,64]
    const float* emb = (const float*)d_in[1];   // [1024,64]
    const float* cc  = (const float*)d_in[2];   // [1024]
    float* out = (float*)d_out;
    float* ws  = (float*)d_ws;

    vq_prep_ortho<<<32, 256, 0, stream>>>(emb, cc, ws);
    vq_main<<<(N_ROWS / 64) * NSPLIT, 256, 0, stream>>>(inp, ws);
    vq_combine<<<N_ROWS / 64, 256, 0, stream>>>(inp, emb, ws, out);
    vq_finalize<<<1, 256, 0, stream>>>(ws, cc, out);
}

// Round 9
// 126.698 us; speedup vs baseline: 1.4798x; 1.4584x over previous
//
#include <hip/hip_runtime.h>
#include <math.h>

#define N_ROWS  32768
#define K_CODES 1024
#define D_DIM   64
#define NSPLIT  4            // K-splits (256 codes each)
#define C_SHIFT 30.0f        // logit shift keeps exp2 in fp32 range
#define LOG2E_F 1.4426950408889634f
#define LN2_F   0.6931471805599453f
#define TAU     0.25f        // rescue threshold (base-2 logit units)

// ---- ws float-index layout (NO region needs pre-zeroing) ----
#define WS_E2C    6144                    // [1024] ||e||^2 + C_SHIFT (legacy order)
#define PART_STRIDE (NSPLIT * N_ROWS)     // 131072
#define WS_PART_S  8192
#define WS_PART_U  (8192 + PART_STRIDE)
#define WS_PART_AB (8192 + 2 * PART_STRIDE)   // packed i1*1024+i2 (as float)
#define WS_PART_M1 (8192 + 3 * PART_STRIDE)   // approx best value per split
#define WS_PART_M2 (8192 + 4 * PART_STRIDE)   // approx 2nd  value per split
#define CHUNK_F4  260                     // float4s per chunk record
#define MAIN_CHUNKS 16                    // 16-code chunks per K-split
#define WS_EB      (8192 + 5 * PART_STRIDE)    // 663552; 64 chunks x 260 f4
#define WS_GP      (WS_EB + 64 * CHUNK_F4 * 4) // 730112; 16 x 4096 gram partials
#define WS_HB      (WS_GP + 16 * 4096)         // 795648; 16 x 1024 hist partials
#define WS_PH      (WS_HB + 16 * K_CODES)      // 812032; 512 entropy partials
#define WS_PC      (WS_PH + 512)               // 812544; 512 commit partials

// ---- out float-index layout (reference return order, concatenated) ----
#define OUT_Q      0
#define OUT_COMMIT 2097152
#define OUT_ORTHO  2097153
#define OUT_ENT    2097154
#define OUT_PERP   2097155
#define OUT_COV    2097156
#define OUT_IDX    2097157

typedef __attribute__((ext_vector_type(8))) _Float16 f16x8;  // 8 f16 = 4 VGPR
typedef __attribute__((ext_vector_type(4))) float f32x4;

// fp16x2 decomposition of 8 floats -> (hi, mid) f16x8 pair.
__device__ inline void decomp2x8(const float* v, f16x8& h, f16x8& m) {
#pragma unroll
    for (int i = 0; i < 8; ++i) {
        _Float16 hh = (_Float16)v[i];
        h[i] = hh;
        m[i] = (_Float16)(v[i] - (float)hh);
    }
}

// Blocks 0..15: E-fragment fp16x2 decomposition + ||e||^2.
// Blocks 16..31: ortho gram partials -> per-block slots (non-atomic).
__global__ __launch_bounds__(256) void vq_prep_ortho(const float* __restrict__ emb,
                                                     const float* __restrict__ cc,
                                                     float* __restrict__ ws) {
    __shared__ float srows[64][64];
    __shared__ float rn2[64];
    const int t = threadIdx.x;

    if (blockIdx.x < 16) {
        const int tid  = blockIdx.x * 256 + t;            // 0..4095
        const int c    = tid >> 6;
        const int lane = tid & 63;
        const int col  = lane & 15;
        const int kg   = lane >> 4;
        const int code = c * 16 + col;
        float4* EB4 = (float4*)(ws + WS_EB);
#pragma unroll
        for (int s = 0; s < 2; ++s) {
            const float* ep = emb + (size_t)code * D_DIM + s * 32 + kg * 8;
            float4 A4 = *(const float4*)ep;
            float4 B4 = *(const float4*)(ep + 4);
            float v[8] = {A4.x, A4.y, A4.z, A4.w, B4.x, B4.y, B4.z, B4.w};
            union { f16x8 h; float4 f; } th, tm;
            decomp2x8(v, th.h, tm.h);
            const int base = c * CHUNK_F4;
            EB4[base + (s * 2 + 0) * 64 + lane] = th.f;   // hi  frag, k-step s
            EB4[base + (s * 2 + 1) * 64 + lane] = tm.f;   // mid frag, k-step s
        }
        if (kg == 0) {
            // legacy sequential order -> ws[WS_E2C] bitwise matches prior rounds
            const float4* e4 = (const float4*)(emb + (size_t)code * D_DIM);
            float ssum = 0.f;
#pragma unroll
            for (int j = 0; j < 16; ++j) {
                float4 v = e4[j];
                ssum += v.x * v.x + v.y * v.y + v.z * v.z + v.w * v.w;
            }
            float e2c = ssum + C_SHIFT;
            ws[WS_E2C + code] = e2c;
            ((float*)(EB4 + c * CHUNK_F4 + 256))[col] = e2c * LOG2E_F;  // base-2
        }
        return;
    }

    // ---- ortho: block b owns codes [64b, 64b+64); partial 64x64 gram
    const int ob = blockIdx.x - 16;
    const int k0 = ob * 64;
    const int rb = t >> 4;            // 0..15
    const int c4 = (t & 15) << 2;     // float4 col

#pragma unroll
    for (int i = 0; i < 4; ++i) {
        const int r = i * 16 + rb;
        float4 v = *(const float4*)(emb + (size_t)(k0 + r) * D_DIM + c4);
        *(float4*)(&srows[r][c4]) = v;
        float ss = v.x * v.x + v.y * v.y + v.z * v.z + v.w * v.w;
        ss += __shfl_down(ss, 8, 16);
        ss += __shfl_down(ss, 4, 16);
        ss += __shfl_down(ss, 2, 16);
        ss += __shfl_down(ss, 1, 16);
        if ((t & 15) == 0) {
            float nrm = fmaxf(sqrtf(ss), 1e-12f);
            float m = (cc[k0 + r] >= 1.0f) ? 1.0f : 0.0f;
            rn2[r] = m / (nrm * nrm);     // rnorm^2, folded into A side
        }
    }
    __syncthreads();

    const int a  = t >> 2;
    const int b0 = (t & 3) << 4;
    float acc[16];
#pragma unroll
    for (int i = 0; i < 16; ++i) acc[i] = 0.f;

#pragma unroll 4
    for (int k = 0; k < 64; ++k) {
        float na = srows[k][a] * rn2[k];
        const float* rbp = &srows[k][b0];
#pragma unroll
        for (int i = 0; i < 16; ++i) acc[i] = fmaf(na, rbp[i], acc[i]);
    }
#pragma unroll
    for (int i = 0; i < 16; ++i)
        ws[WS_GP + ob * 4096 + a * 64 + b0 + i] = acc[i];   // own slot, no atomic
}

#define MFMA_F16 __builtin_amdgcn_mfma_f32_16x16x32_f16

// 2048 blocks x 256 thr. Block = (row-group of 64, K-split of 256 codes).
// Wave = 16 rows x 256 codes; fp16x2 4-term MFMA emulation. DESIGN-FOR-64.
// Unchanged from r8 (proven absmax 0.0).
__global__ __launch_bounds__(256)
void vq_main(const float* __restrict__ inp, float* __restrict__ ws) {
    const int t    = threadIdx.x;
    const int lane = t & 63;
    const int wave = t >> 6;
    const int col  = lane & 15;
    const int kg   = lane >> 4;
    const int rg   = blockIdx.x >> 2;      // row group 0..511 (64 rows)
    const int sp   = blockIdx.x & 3;       // k split 0..3 (256 codes)
    const int row  = rg * 64 + wave * 16 + col;

    // A-frags: hi/mid per k-step
    f16x8 xh0, xm0, xh1, xm1;
    {
        const float* xp = inp + (size_t)row * D_DIM + kg * 8;
        float4 A4 = *(const float4*)xp;
        float4 B4 = *(const float4*)(xp + 4);
        float v[8] = {A4.x, A4.y, A4.z, A4.w, B4.x, B4.y, B4.z, B4.w};
        decomp2x8(v, xh0, xm0);
        A4 = *(const float4*)(xp + 32);
        B4 = *(const float4*)(xp + 36);
        float w[8] = {A4.x, A4.y, A4.z, A4.w, B4.x, B4.y, B4.z, B4.w};
        decomp2x8(w, xh1, xm1);
    }

    const float4* EBp = (const float4*)(ws + WS_EB)
                      + (size_t)sp * MAIN_CHUNKS * CHUNK_F4;

    float sa[4], ua[4], m1[4], m2[4];
    int i12[4];
#pragma unroll
    for (int q = 0; q < 4; ++q) {
        sa[q] = 0.f; ua[q] = 0.f;
        m1[q] = -1e30f; m2[q] = -1e30f;
        i12[q] = 0;
    }

#pragma unroll 1
    for (int c = 0; c < MAIN_CHUNKS; ++c) {
        const float4* p = EBp + (size_t)c * CHUNK_F4;
        const f16x8* pb = (const f16x8*)p;
        f16x8 bh0 = pb[0 * 64 + lane];     // hi,  k-step 0
        f16x8 bm0 = pb[1 * 64 + lane];     // mid, k-step 0
        f16x8 bh1 = pb[2 * 64 + lane];     // hi,  k-step 1
        f16x8 bm1 = pb[3 * 64 + lane];     // mid, k-step 1
        const float e2v = ((const float*)(p + 256))[col];

        f32x4 acc = {0.f, 0.f, 0.f, 0.f};
        acc = MFMA_F16(xh0, bh0, acc, 0, 0, 0);
        acc = MFMA_F16(xh1, bh1, acc, 0, 0, 0);
        acc = MFMA_F16(xm0, bh0, acc, 0, 0, 0);
        acc = MFMA_F16(xm1, bh1, acc, 0, 0, 0);
        acc = MFMA_F16(xh0, bm0, acc, 0, 0, 0);
        acc = MFMA_F16(xh1, bm1, acc, 0, 0, 0);
        acc = MFMA_F16(xm0, bm0, acc, 0, 0, 0);
        acc = MFMA_F16(xm1, bm1, acc, 0, 0, 0);

        const int cb = sp * 256 + c * 16 + col;        // global code index
#pragma unroll
        for (int q = 0; q < 4; ++q) {
            // base-2 shifted logit: g = 2*log2e*dot - log2e*(e2+C_SHIFT)
            float g = fmaf(2.0f * LOG2E_F, acc[q], -e2v);
            float pw;
            asm("v_exp_f32 %0, %1" : "=v"(pw) : "v"(g));   // 2^g
            sa[q] += pw;
            ua[q] = fmaf(pw, g, ua[q]);
            bool gt1 = g > m1[q];
            bool gt2 = g > m2[q];
            int t1 = (cb << 10) | (i12[q] >> 10);          // new i1=cb, i2=old i1
            int t2 = (i12[q] & ~1023) | cb;                // new i2=cb
            i12[q] = gt1 ? t1 : (gt2 ? t2 : i12[q]);
            m2[q] = __builtin_amdgcn_fmed3f(g, m2[q], m1[q]);
            m1[q] = fmaxf(m1[q], g);
        }
    }

    // per-row reduce across the 16 lanes sharing each C-row
#pragma unroll
    for (int off = 1; off < 16; off <<= 1) {
#pragma unroll
        for (int q = 0; q < 4; ++q) {
            sa[q] += __shfl_xor(sa[q], off);
            ua[q] += __shfl_xor(ua[q], off);
            float bm1v = __shfl_xor(m1[q], off);
            float bm2v = __shfl_xor(m2[q], off);
            int   biv  = __shfl_xor(i12[q], off);
            if (bm1v > m1[q]) {
                if (bm2v > m1[q]) {            // both from partner
                    m2[q] = bm2v; i12[q] = biv;
                } else {                        // partner's 1st, our 1st
                    m2[q] = m1[q];
                    i12[q] = (biv & ~1023 & 0xFFFFFC00) | (i12[q] >> 10);
                    i12[q] = ((biv >> 10) << 10) | (i12[q] & 1023);
                }
                m1[q] = bm1v;
            } else if (bm1v > m2[q]) {          // partner's 1st is our 2nd
                m2[q] = bm1v;
                i12[q] = (i12[q] & ~1023) | (biv >> 10);
            }
        }
    }

    if (col == 0) {
#pragma unroll
        for (int q = 0; q < 4; ++q) {
            const int r  = rg * 64 + wave * 16 + kg * 4 + q;
            const int pi = sp * N_ROWS + r;
            ws[WS_PART_S  + pi] = sa[q];
            ws[WS_PART_U  + pi] = ua[q];
            ws[WS_PART_AB + pi] = (float)i12[q];
            ws[WS_PART_M1 + pi] = m1[q];
            ws[WS_PART_M2 + pi] = m2[q];
        }
    }
}

// 512 blocks x 256 thr; QUAD (4 lanes) per row. Structure identical to r8
// EXCEPT: zero global atomics. Hist moved to vq_hist; H/commit accumulate
// via LDS block-reduce into per-block slots (plain stores).
__global__ __launch_bounds__(256) void vq_combine(const float* __restrict__ inp,
                                                  const float* __restrict__ emb,
                                                  float* __restrict__ ws,
                                                  float* __restrict__ out) {
    __shared__ float shH[4], shC[4];
    const int t    = threadIdx.x;
    const int lane = t & 63;
    const int wave = t >> 6;
    const int l    = t & 3;               // quad lane = chain id
    const int row  = blockIdx.x * 64 + (t >> 2);
    const int qb   = lane & ~3;           // quad base within wave

    // this lane's split-l partials
    const int pi = l * N_ROWS + row;
    float Sl  = ws[WS_PART_S  + pi];
    float Ul  = ws[WS_PART_U  + pi];
    int   ab  = (int)ws[WS_PART_AB + pi];
    float M1l = ws[WS_PART_M1 + pi];
    float M2l = ws[WS_PART_M2 + pi];

    // quad gather: S,U in ascending split order (legacy); Gmax over splits
    float S = 0.f, U2 = 0.f, Gmax = -1e30f;
#pragma unroll
    for (int k = 0; k < 4; ++k) {
        S  += __shfl(Sl, qb + k);
        U2 += __shfl(Ul, qb + k);
        Gmax = fmaxf(Gmax, __shfl(M1l, qb + k));
    }

    // X strided quarter: Xq[k] = X[l + 4k] (serves chains + write + commit)
    float4 Xq[4];
    const float4* xr = (const float4*)(inp + (size_t)row * D_DIM);
#pragma unroll
    for (int k = 0; k < 4; ++k) Xq[k] = xr[l + 4 * k];

    // candidates in legacy order j=0..7 (split asc, i1 before i2)
    float bestg = -1e30f; int I = K_CODES;
#pragma unroll 1
    for (int j = 0; j < 8; ++j) {
        const int sp  = j >> 1;
        const float v = __shfl((j & 1) ? M2l : M1l, qb + sp);
        if (v < Gmax - TAU) continue;      // provably cannot be exact argmax
        const int abo = __shfl(ab, qb + sp);
        const int c   = (j & 1) ? (abo & 1023) : (abo >> 10);
        // lane l: legacy chain d_l = fma chain over e4[l+4k] x X[l+4k]
        const float4* e4 = (const float4*)(emb + (size_t)c * D_DIM);
        float d = 0.f;
#pragma unroll
        for (int k = 0; k < 4; ++k) {
            float4 ev = e4[l + 4 * k];
            float4 xv = Xq[k];
            d = fmaf(ev.x, xv.x, d); d = fmaf(ev.y, xv.y, d);
            d = fmaf(ev.z, xv.z, d); d = fmaf(ev.w, xv.w, d);
        }
        float dA = __shfl(d, qb + 0) + __shfl(d, qb + 1);   // (d0+d1)
        float dB = __shfl(d, qb + 2) + __shfl(d, qb + 3);   // (d2+d3)
        float g  = fmaf(2.0f, dA + dB, -ws[WS_E2C + c]);    // legacy-exact
        if (g > bestg || (g == bestg && c < I)) { bestg = g; I = c; }
    }

    float H = logf(S) - (U2 * LN2_F) / S;  // per-row entropy (nats)

    if (l == 0) out[OUT_IDX + row] = (float)I;

    // quantized + commitment on the strided quarter (elementwise-identical Q)
    const float4* q4 = (const float4*)(emb + (size_t)I * D_DIM);
    float4* oq = (float4*)out + (size_t)row * 16;
    float cs = 0.f;
#pragma unroll
    for (int k = 0; k < 4; ++k) {
        float4 q = q4[l + 4 * k], x = Xq[k];
        float dx = q.x - x.x, dy = q.y - x.y, dz = q.z - x.z, dw = q.w - x.w;
        cs += dx * dx + dy * dy + dz * dz + dw * dw;
        float4 o;
        o.x = x.x + dx; o.y = x.y + dy; o.z = x.z + dz; o.w = x.w + dw;
        oq[l + 4 * k] = o;
    }

    float Hc = (l == 0) ? H : 0.f;
#pragma unroll
    for (int off = 32; off; off >>= 1) {
        Hc += __shfl_down(Hc, off);
        cs += __shfl_down(cs, off);
    }
    if (lane == 0) { shH[wave] = Hc; shC[wave] = cs; }
    __syncthreads();
    if (t == 0) {
        ws[WS_PH + blockIdx.x] = shH[0] + shH[1] + shH[2] + shH[3];
        ws[WS_PC + blockIdx.x] = shC[0] + shC[1] + shC[2] + shC[3];
    }
}

// 16 blocks x 256 thr; block b LDS-histograms rows [2048b, 2048b+2048) from
// OUT_IDX, writes its 1024-bucket partial to a private slot. No global atomics.
__global__ __launch_bounds__(256) void vq_hist(const float* __restrict__ out,
                                               float* __restrict__ ws) {
    __shared__ int h[K_CODES];
    const int t = threadIdx.x;
#pragma unroll
    for (int i = 0; i < 4; ++i) h[t + 256 * i] = 0;
    __syncthreads();
    const int base = blockIdx.x * 2048;
#pragma unroll
    for (int i = 0; i < 8; ++i) {
        int idx = (int)out[OUT_IDX + base + t + 256 * i];
        atomicAdd(&h[idx], 1);                          // LDS atomic only
    }
    __syncthreads();
#pragma unroll
    for (int i = 0; i < 4; ++i) {
        const int k = t + 256 * i;
        ws[WS_HB + blockIdx.x * K_CODES + k] = (float)h[k];
    }
}

// 1 block x 256 thr. Plain loads only: every input written by prior dispatches.
__global__ __launch_bounds__(256) void vq_finalize(const float* __restrict__ ws,
                                                   const float* __restrict__ cc,
                                                   float* __restrict__ out) {
    __shared__ float red[5][4];
    const int t = threadIdx.x;
    float hp = 0.f, gg = 0.f, nu = 0.f, hh = 0.f, cm = 0.f;
    for (int k = t; k < K_CODES; k += 256) {
        float s = 0.f;
#pragma unroll
        for (int b = 0; b < 16; ++b) s += ws[WS_HB + b * K_CODES + k];
        float p = s * (1.0f / (float)N_ROWS);
        hp += p * logf(p + 1e-10f);
        nu += (cc[k] >= 1.0f) ? 1.0f : 0.0f;
    }
    for (int i = t; i < 4096; i += 256) {
        float s = 0.f;
#pragma unroll
        for (int b = 0; b < 16; ++b) s += ws[WS_GP + b * 4096 + i];
        gg = fmaf(s, s, gg);
    }
    for (int i = t; i < 512; i += 256) {
        hh += ws[WS_PH + i];
        cm += ws[WS_PC + i];
    }
#pragma unroll
    for (int off = 32; off; off >>= 1) {
        hp += __shfl_down(hp, off);
        gg += __shfl_down(gg, off);
        nu += __shfl_down(nu, off);
        hh += __shfl_down(hh, off);
        cm += __shfl_down(cm, off);
    }
    if ((t & 63) == 0) {
        const int w = t >> 6;
        red[0][w] = hp; red[1][w] = gg; red[2][w] = nu;
        red[3][w] = hh; red[4][w] = cm;
    }
    __syncthreads();
    if (t == 0) {
        float hsum = red[0][0] + red[0][1] + red[0][2] + red[0][3];
        float gsum = red[1][0] + red[1][1] + red[1][2] + red[1][3];
        float nuv  = red[2][0] + red[2][1] + red[2][2] + red[2][3];
        float hacc = red[3][0] + red[3][1] + red[3][2] + red[3][3];
        float cacc = red[4][0] + red[4][1] + red[4][2] + red[4][3];
        out[OUT_PERP]   = expf(-hsum);
        out[OUT_ENT]    = hacc * (1.0f / (float)N_ROWS) * 0.1f; // /log2(1024)
        out[OUT_COMMIT] = cacc * (1.0f / ((float)N_ROWS * (float)D_DIM));
        out[OUT_ORTHO]  = gsum / (nuv * nuv) - 1.0f / nuv;
        out[OUT_COV]    = nuv * (1.0f / (float)K_CODES);
    }
}

extern "C" void kernel_launch(void* const* d_in, const int* in_sizes, int n_in,
                              void* d_out, int out_size, void* d_ws, size_t ws_size,
                              hipStream_t stream) {
    const float* inp = (const float*)d_in[0];   // [16,2048,64]
    const float* emb = (const float*)d_in[1];   // [1024,64]
    const float* cc  = (const float*)d_in[2];   // [1024]
    float* out = (float*)d_out;
    float* ws  = (float*)d_ws;

    vq_prep_ortho<<<32, 256, 0, stream>>>(emb, cc, ws);
    vq_main<<<(N_ROWS / 64) * NSPLIT, 256, 0, stream>>>(inp, ws);
    vq_combine<<<N_ROWS / 64, 256, 0, stream>>>(inp, emb, ws, out);
    vq_hist<<<16, 256, 0, stream>>>(out, ws);
    vq_finalize<<<1, 256, 0, stream>>>(ws, cc, out);
}

// Round 11
// 119.317 us; speedup vs baseline: 1.5713x; 1.0619x over previous
//
#include <hip/hip_runtime.h>
#include <math.h>

#define N_ROWS  32768
#define K_CODES 1024
#define D_DIM   64
#define NSPLIT  4            // K-splits (256 codes each)
#define C_SHIFT 30.0f        // logit shift keeps exp2 in fp32 range
#define LOG2E_F 1.4426950408889634f
#define LN2_F   0.6931471805599453f
#define TAU     0.25f        // rescue threshold (base-2 logit units)

// ---- ws float-index layout (NO region needs pre-zeroing) ----
#define WS_E2C    6144                    // [1024] ||e||^2 + C_SHIFT (legacy order)
#define PART_STRIDE (NSPLIT * N_ROWS)     // 131072
#define WS_PART_S  8192
#define WS_PART_U  (8192 + PART_STRIDE)
#define WS_PART_M1 (8192 + 2 * PART_STRIDE)   // top-1 key (u32 bits in float slot)
#define WS_PART_M2 (8192 + 3 * PART_STRIDE)   // top-2 key
#define CHUNK_F4  260                     // float4s per chunk record
#define MAIN_CHUNKS 16                    // 16-code chunks per K-split
#define WS_EB      (8192 + 4 * PART_STRIDE)    // 532480; 64 chunks x 260 f4
#define WS_GP      (WS_EB + 64 * CHUNK_F4 * 4) // 599040; 16 x 4096 gram partials
#define WS_HB      (WS_GP + 16 * 4096)         // 664576; 16 x 1024 hist partials
#define WS_PH      (WS_HB + 16 * K_CODES)      // 680960; 512 entropy partials
#define WS_PC      (WS_PH + 512)               // 681472; 512 commit partials

// ---- out float-index layout (reference return order, concatenated) ----
#define OUT_Q      0
#define OUT_COMMIT 2097152
#define OUT_ORTHO  2097153
#define OUT_ENT    2097154
#define OUT_PERP   2097155
#define OUT_COV    2097156
#define OUT_IDX    2097157

typedef __attribute__((ext_vector_type(8))) _Float16 f16x8;  // 8 f16 = 4 VGPR
typedef __attribute__((ext_vector_type(4))) float f32x4;

__device__ inline unsigned umaxu(unsigned a, unsigned b) { return a > b ? a : b; }
__device__ inline unsigned uminu(unsigned a, unsigned b) { return a < b ? a : b; }

// inverse of the monotone float->u32 map (for TAU screening in combine)
__device__ inline float keyval(unsigned u) {
    unsigned b = (u & 0x80000000u) ? (u ^ 0x80000000u) : ~u;
    return __uint_as_float(b);
}

// fp16x2 decomposition of 8 floats -> (hi, mid) f16x8 pair.
__device__ inline void decomp2x8(const float* v, f16x8& h, f16x8& m) {
#pragma unroll
    for (int i = 0; i < 8; ++i) {
        _Float16 hh = (_Float16)v[i];
        h[i] = hh;
        m[i] = (_Float16)(v[i] - (float)hh);
    }
}

// Blocks 0..15: E-fragment fp16x2 decomposition + ||e||^2.
// Blocks 16..31: ortho gram partials -> per-block slots (non-atomic).
__global__ __launch_bounds__(256) void vq_prep_ortho(const float* __restrict__ emb,
                                                     const float* __restrict__ cc,
                                                     float* __restrict__ ws) {
    __shared__ float srows[64][64];
    __shared__ float rn2[64];
    const int t = threadIdx.x;

    if (blockIdx.x < 16) {
        const int tid  = blockIdx.x * 256 + t;            // 0..4095
        const int c    = tid >> 6;
        const int lane = tid & 63;
        const int col  = lane & 15;
        const int kg   = lane >> 4;
        const int code = c * 16 + col;
        float4* EB4 = (float4*)(ws + WS_EB);
#pragma unroll
        for (int s = 0; s < 2; ++s) {
            const float* ep = emb + (size_t)code * D_DIM + s * 32 + kg * 8;
            float4 A4 = *(const float4*)ep;
            float4 B4 = *(const float4*)(ep + 4);
            float v[8] = {A4.x, A4.y, A4.z, A4.w, B4.x, B4.y, B4.z, B4.w};
            union { f16x8 h; float4 f; } th, tm;
            decomp2x8(v, th.h, tm.h);
            const int base = c * CHUNK_F4;
            EB4[base + (s * 2 + 0) * 64 + lane] = th.f;   // hi  frag, k-step s
            EB4[base + (s * 2 + 1) * 64 + lane] = tm.f;   // mid frag, k-step s
        }
        if (kg == 0) {
            // legacy sequential order -> ws[WS_E2C] bitwise matches prior rounds
            const float4* e4 = (const float4*)(emb + (size_t)code * D_DIM);
            float ssum = 0.f;
#pragma unroll
            for (int j = 0; j < 16; ++j) {
                float4 v = e4[j];
                ssum += v.x * v.x + v.y * v.y + v.z * v.z + v.w * v.w;
            }
            float e2c = ssum + C_SHIFT;
            ws[WS_E2C + code] = e2c;
            ((float*)(EB4 + c * CHUNK_F4 + 256))[col] = e2c * LOG2E_F;  // base-2
        }
        return;
    }

    // ---- ortho: block b owns codes [64b, 64b+64); partial 64x64 gram
    const int ob = blockIdx.x - 16;
    const int k0 = ob * 64;
    const int rb = t >> 4;            // 0..15
    const int c4 = (t & 15) << 2;     // float4 col

#pragma unroll
    for (int i = 0; i < 4; ++i) {
        const int r = i * 16 + rb;
        float4 v = *(const float4*)(emb + (size_t)(k0 + r) * D_DIM + c4);
        *(float4*)(&srows[r][c4]) = v;
        float ss = v.x * v.x + v.y * v.y + v.z * v.z + v.w * v.w;
        ss += __shfl_down(ss, 8, 16);
        ss += __shfl_down(ss, 4, 16);
        ss += __shfl_down(ss, 2, 16);
        ss += __shfl_down(ss, 1, 16);
        if ((t & 15) == 0) {
            float nrm = fmaxf(sqrtf(ss), 1e-12f);
            float m = (cc[k0 + r] >= 1.0f) ? 1.0f : 0.0f;
            rn2[r] = m / (nrm * nrm);     // rnorm^2, folded into A side
        }
    }
    __syncthreads();

    const int a  = t >> 2;
    const int b0 = (t & 3) << 4;
    float acc[16];
#pragma unroll
    for (int i = 0; i < 16; ++i) acc[i] = 0.f;

#pragma unroll 4
    for (int k = 0; k < 64; ++k) {
        float na = srows[k][a] * rn2[k];
        const float* rbp = &srows[k][b0];
#pragma unroll
        for (int i = 0; i < 16; ++i) acc[i] = fmaf(na, rbp[i], acc[i]);
    }
#pragma unroll
    for (int i = 0; i < 16; ++i)
        ws[WS_GP + ob * 4096 + a * 64 + b0 + i] = acc[i];   // own slot, no atomic
}

#define MFMA_F16 __builtin_amdgcn_mfma_f32_16x16x32_f16

// 2048 blocks x 256 thr. Block = (row-group of 64, K-split of 256 codes).
// Wave = 16 rows x 256 codes; fp16x2 4-term MFMA emulation.
// Top-2 tracking via index-embedded monotone u32 keys: kills i12[4] (8 regs)
// + the branchy merge. State = sa/ua/m1/m2 = 16 regs; total demand ~58 <=
// the 8-wave 64-reg unified budget -> no AGPR shuttle (r9: VGPR=36 + 2x
// VALU inflation = state eviction at this tier).
__global__ __launch_bounds__(256)
void vq_main(const float* __restrict__ inp, float* __restrict__ ws) {
    const int t    = threadIdx.x;
    const int lane = t & 63;
    const int wave = t >> 6;
    const int col  = lane & 15;
    const int kg   = lane >> 4;
    const int rg   = blockIdx.x >> 2;      // row group 0..511 (64 rows)
    const int sp   = blockIdx.x & 3;       // k split 0..3 (256 codes)
    const int row  = rg * 64 + wave * 16 + col;

    // A-frags: hi/mid per k-step
    f16x8 xh0, xm0, xh1, xm1;
    {
        const float* xp = inp + (size_t)row * D_DIM + kg * 8;
        float4 A4 = *(const float4*)xp;
        float4 B4 = *(const float4*)(xp + 4);
        float v[8] = {A4.x, A4.y, A4.z, A4.w, B4.x, B4.y, B4.z, B4.w};
        decomp2x8(v, xh0, xm0);
        A4 = *(const float4*)(xp + 32);
        B4 = *(const float4*)(xp + 36);
        float w[8] = {A4.x, A4.y, A4.z, A4.w, B4.x, B4.y, B4.z, B4.w};
        decomp2x8(w, xh1, xm1);
    }

    const float4* EBp = (const float4*)(ws + WS_EB)
                      + (size_t)sp * MAIN_CHUNKS * CHUNK_F4;

    float sa[4], ua[4];
    unsigned m1[4], m2[4];
#pragma unroll
    for (int q = 0; q < 4; ++q) {
        sa[q] = 0.f; ua[q] = 0.f;
        m1[q] = 0u; m2[q] = 0u;     // below any finite key
    }

#pragma unroll 1
    for (int c = 0; c < MAIN_CHUNKS; ++c) {
        const float4* p = EBp + (size_t)c * CHUNK_F4;
        const f16x8* pb = (const f16x8*)p;
        f16x8 bh0 = pb[0 * 64 + lane];     // hi,  k-step 0
        f16x8 bm0 = pb[1 * 64 + lane];     // mid, k-step 0
        f16x8 bh1 = pb[2 * 64 + lane];     // hi,  k-step 1
        f16x8 bm1 = pb[3 * 64 + lane];     // mid, k-step 1
        const float e2v = ((const float*)(p + 256))[col];

        f32x4 acc = {0.f, 0.f, 0.f, 0.f};
        acc = MFMA_F16(xh0, bh0, acc, 0, 0, 0);
        acc = MFMA_F16(xh1, bh1, acc, 0, 0, 0);
        acc = MFMA_F16(xm0, bh0, acc, 0, 0, 0);
        acc = MFMA_F16(xm1, bh1, acc, 0, 0, 0);
        acc = MFMA_F16(xh0, bm0, acc, 0, 0, 0);
        acc = MFMA_F16(xh1, bm1, acc, 0, 0, 0);
        acc = MFMA_F16(xm0, bm0, acc, 0, 0, 0);
        acc = MFMA_F16(xm1, bm1, acc, 0, 0, 0);

        // embed value: same for all q (code = c*16+col, split-local, 8 bits);
        // inverted so smaller code -> larger key -> legacy first-index ties
        const unsigned embedv = 255u - (unsigned)(c * 16 + col);
#pragma unroll
        for (int q = 0; q < 4; ++q) {
            // base-2 shifted logit: g = 2*log2e*dot - log2e*(e2+C_SHIFT)
            float g = fmaf(2.0f * LOG2E_F, acc[q], -e2v);
            float pw;
            asm("v_exp_f32 %0, %1" : "=v"(pw) : "v"(g));   // 2^g
            sa[q] += pw;
            ua[q] = fmaf(pw, g, ua[q]);
            // monotone key with embedded code (low-8 clear = <=1e-3 perturb,
            // screened by TAU with 60x margin in combine)
            int gb = __float_as_int(g);
            unsigned u = (unsigned)(gb ^ ((gb >> 31) | 0x80000000));
            unsigned key = (u & 0xFFFFFF00u) | embedv;
            m2[q] = uminu(umaxu(key, m2[q]), m1[q]);   // med3(key, m2, m1)
            m1[q] = umaxu(m1[q], key);
        }
    }

    // per-row reduce across the 16 lanes sharing each C-row:
    // branch-free 2-way sorted-pair merge on keys
#pragma unroll
    for (int off = 1; off < 16; off <<= 1) {
#pragma unroll
        for (int q = 0; q < 4; ++q) {
            sa[q] += __shfl_xor(sa[q], off);
            ua[q] += __shfl_xor(ua[q], off);
            unsigned p1 = (unsigned)__shfl_xor((int)m1[q], off);
            unsigned p2 = (unsigned)__shfl_xor((int)m2[q], off);
            unsigned lo = uminu(m1[q], p1);
            m1[q] = umaxu(m1[q], p1);
            m2[q] = umaxu(lo, umaxu(m2[q], p2));
        }
    }

    if (col == 0) {
#pragma unroll
        for (int q = 0; q < 4; ++q) {
            const int r  = rg * 64 + wave * 16 + kg * 4 + q;
            const int pi = sp * N_ROWS + r;
            ws[WS_PART_S  + pi] = sa[q];
            ws[WS_PART_U  + pi] = ua[q];
            ws[WS_PART_M1 + pi] = __uint_as_float(m1[q]);
            ws[WS_PART_M2 + pi] = __uint_as_float(m2[q]);
        }
    }
}

// 512 blocks x 256 thr; QUAD (4 lanes) per row. Zero global atomics (r9).
// Candidates decoded straight from the keys (AB array gone).
__global__ __launch_bounds__(256) void vq_combine(const float* __restrict__ inp,
                                                  const float* __restrict__ emb,
                                                  float* __restrict__ ws,
                                                  float* __restrict__ out) {
    __shared__ float shH[4], shC[4];
    const int t    = threadIdx.x;
    const int lane = t & 63;
    const int wave = t >> 6;
    const int l    = t & 3;               // quad lane = chain id
    const int row  = blockIdx.x * 64 + (t >> 2);
    const int qb   = lane & ~3;           // quad base within wave

    // this lane's split-l partials
    const int pi = l * N_ROWS + row;
    float    Sl = ws[WS_PART_S  + pi];
    float    Ul = ws[WS_PART_U  + pi];
    unsigned K1 = __float_as_uint(ws[WS_PART_M1 + pi]);
    unsigned K2 = __float_as_uint(ws[WS_PART_M2 + pi]);
    float    G1 = keyval(K1);

    // quad gather: S,U in ascending split order (legacy); Gmax over splits
    float S = 0.f, U2 = 0.f, Gmax = -1e30f;
#pragma unroll
    for (int k = 0; k < 4; ++k) {
        S  += __shfl(Sl, qb + k);
        U2 += __shfl(Ul, qb + k);
        Gmax = fmaxf(Gmax, __shfl(G1, qb + k));
    }

    // X strided quarter: Xq[k] = X[l + 4k] (serves chains + write + commit)
    float4 Xq[4];
    const float4* xr = (const float4*)(inp + (size_t)row * D_DIM);
#pragma unroll
    for (int k = 0; k < 4; ++k) Xq[k] = xr[l + 4 * k];

    // candidates in legacy order j=0..7 (split asc, rank-1 before rank-2)
    float bestg = -1e30f; int I = K_CODES;
#pragma unroll 1
    for (int j = 0; j < 8; ++j) {
        const int sp = j >> 1;
        const unsigned kk = (unsigned)__shfl((int)((j & 1) ? K2 : K1), qb + sp);
        const float v = keyval(kk);
        if (v < Gmax - TAU) continue;      // provably cannot be exact argmax
        const int c = sp * 256 + 255 - (int)(kk & 255u);
        // lane l: legacy chain d_l = fma chain over e4[l+4k] x X[l+4k]
        const float4* e4 = (const float4*)(emb + (size_t)c * D_DIM);
        float d = 0.f;
#pragma unroll
        for (int k = 0; k < 4; ++k) {
            float4 ev = e4[l + 4 * k];
            float4 xv = Xq[k];
            d = fmaf(ev.x, xv.x, d); d = fmaf(ev.y, xv.y, d);
            d = fmaf(ev.z, xv.z, d); d = fmaf(ev.w, xv.w, d);
        }
        float dA = __shfl(d, qb + 0) + __shfl(d, qb + 1);   // (d0+d1)
        float dB = __shfl(d, qb + 2) + __shfl(d, qb + 3);   // (d2+d3)
        float g  = fmaf(2.0f, dA + dB, -ws[WS_E2C + c]);    // legacy-exact
        if (g > bestg || (g == bestg && c < I)) { bestg = g; I = c; }
    }

    float H = logf(S) - (U2 * LN2_F) / S;  // per-row entropy (nats)

    if (l == 0) out[OUT_IDX + row] = (float)I;

    // quantized + commitment on the strided quarter (elementwise-identical Q)
    const float4* q4 = (const float4*)(emb + (size_t)I * D_DIM);
    float4* oq = (float4*)out + (size_t)row * 16;
    float cs = 0.f;
#pragma unroll
    for (int k = 0; k < 4; ++k) {
        float4 q = q4[l + 4 * k], x = Xq[k];
        float dx = q.x - x.x, dy = q.y - x.y, dz = q.z - x.z, dw = q.w - x.w;
        cs += dx * dx + dy * dy + dz * dz + dw * dw;
        float4 o;
        o.x = x.x + dx; o.y = x.y + dy; o.z = x.z + dz; o.w = x.w + dw;
        oq[l + 4 * k] = o;
    }

    float Hc = (l == 0) ? H : 0.f;
#pragma unroll
    for (int off = 32; off; off >>= 1) {
        Hc += __shfl_down(Hc, off);
        cs += __shfl_down(cs, off);
    }
    if (lane == 0) { shH[wave] = Hc; shC[wave] = cs; }
    __syncthreads();
    if (t == 0) {
        ws[WS_PH + blockIdx.x] = shH[0] + shH[1] + shH[2] + shH[3];
        ws[WS_PC + blockIdx.x] = shC[0] + shC[1] + shC[2] + shC[3];
    }
}

// 16 blocks x 256 thr; block b LDS-histograms rows [2048b, 2048b+2048) from
// OUT_IDX, writes its 1024-bucket partial to a private slot. No global atomics.
__global__ __launch_bounds__(256) void vq_hist(const float* __restrict__ out,
                                               float* __restrict__ ws) {
    __shared__ int h[K_CODES];
    const int t = threadIdx.x;
#pragma unroll
    for (int i = 0; i < 4; ++i) h[t + 256 * i] = 0;
    __syncthreads();
    const int base = blockIdx.x * 2048;
#pragma unroll
    for (int i = 0; i < 8; ++i) {
        int idx = (int)out[OUT_IDX + base + t + 256 * i];
        atomicAdd(&h[idx], 1);                          // LDS atomic only
    }
    __syncthreads();
#pragma unroll
    for (int i = 0; i < 4; ++i) {
        const int k = t + 256 * i;
        ws[WS_HB + blockIdx.x * K_CODES + k] = (float)h[k];
    }
}

// 1 block x 256 thr. Plain loads only: every input written by prior dispatches.
__global__ __launch_bounds__(256) void vq_finalize(const float* __restrict__ ws,
                                                   const float* __restrict__ cc,
                                                   float* __restrict__ out) {
    __shared__ float red[5][4];
    const int t = threadIdx.x;
    float hp = 0.f, gg = 0.f, nu = 0.f, hh = 0.f, cm = 0.f;
    for (int k = t; k < K_CODES; k += 256) {
        float s = 0.f;
#pragma unroll
        for (int b = 0; b < 16; ++b) s += ws[WS_HB + b * K_CODES + k];
        float p = s * (1.0f / (float)N_ROWS);
        hp += p * logf(p + 1e-10f);
        nu += (cc[k] >= 1.0f) ? 1.0f : 0.0f;
    }
    for (int i = t; i < 4096; i += 256) {
        float s = 0.f;
#pragma unroll
        for (int b = 0; b < 16; ++b) s += ws[WS_GP + b * 4096 + i];
        gg = fmaf(s, s, gg);
    }
    for (int i = t; i < 512; i += 256) {
        hh += ws[WS_PH + i];
        cm += ws[WS_PC + i];
    }
#pragma unroll
    for (int off = 32; off; off >>= 1) {
        hp += __shfl_down(hp, off);
        gg += __shfl_down(gg, off);
        nu += __shfl_down(nu, off);
        hh += __shfl_down(hh, off);
        cm += __shfl_down(cm, off);
    }
    if ((t & 63) == 0) {
        const int w = t >> 6;
        red[0][w] = hp; red[1][w] = gg; red[2][w] = nu;
        red[3][w] = hh; red[4][w] = cm;
    }
    __syncthreads();
    if (t == 0) {
        float hsum = red[0][0] + red[0][1] + red[0][2] + red[0][3];
        float gsum = red[1][0] + red[1][1] + red[1][2] + red[1][3];
        float nuv  = red[2][0] + red[2][1] + red[2][2] + red[2][3];
        float hacc = red[3][0] + red[3][1] + red[3][2] + red[3][3];
        float cacc = red[4][0] + red[4][1] + red[4][2] + red[4][3];
        out[OUT_PERP]   = expf(-hsum);
        out[OUT_ENT]    = hacc * (1.0f / (float)N_ROWS) * 0.1f; // /log2(1024)
        out[OUT_COMMIT] = cacc * (1.0f / ((float)N_ROWS * (float)D_DIM));
        out[OUT_ORTHO]  = gsum / (nuv * nuv) - 1.0f / nuv;
        out[OUT_COV]    = nuv * (1.0f / (float)K_CODES);
    }
}

extern "C" void kernel_launch(void* const* d_in, const int* in_sizes, int n_in,
                              void* d_out, int out_size, void* d_ws, size_t ws_size,
                              hipStream_t stream) {
    const float* inp = (const float*)d_in[0];   // [16,2048,64]
    const float* emb = (const float*)d_in[1];   // [1024,64]
    const float* cc  = (const float*)d_in[2];   // [1024]
    float* out = (float*)d_out;
    float* ws  = (float*)d_ws;

    vq_prep_ortho<<<32, 256, 0, stream>>>(emb, cc, ws);
    vq_main<<<(N_ROWS / 64) * NSPLIT, 256, 0, stream>>>(inp, ws);
    vq_combine<<<N_ROWS / 64, 256, 0, stream>>>(inp, emb, ws, out);
    vq_hist<<<16, 256, 0, stream>>>(out, ws);
    vq_finalize<<<1, 256, 0, stream>>>(ws, cc, out);
}